// Round 6
// baseline (242.879 us; speedup 1.0000x reference)
//
#include <hip/hip_runtime.h>

// MHA: B=2, S=2048, D=1024, H=16, DK=64. All GEMMs are x @ W.T (+bias).
// R14: pipeline shortened 4 -> 3 kernels. cvt_all is gone: gemm_core now
//  converts f32 operands DURING staging (reg-stage: 2x float4 load ->
//  4x cvt_pkrtz -> ds_write_b128; bit-identical RTZ numerics to the old
//  cvt pass). proj3 reads q/k/v and Wq/Wk/Wv directly as f32; out_gemm
//  reads wo f32 (its A = ctx stays f16 via global_load_lds). Removes the
//  28672-block cvt launch, one kernel gap, a 96 MB intermediate pass, and
//  4 workspace buffers. attn unchanged from R13 (49.9us local optimum).
//  R13 gains kept: (m,n) grid -> XCD-local A-reuse; vectorized epilogues.

#define S_LEN 2048
#define BATCH 2
#define DM    1024
#define NH    16
#define DKH   64
#define BS    (BATCH * S_LEN)   // 4096 rows

typedef _Float16 f16x8 __attribute__((ext_vector_type(8)));
typedef _Float16 f16x4 __attribute__((ext_vector_type(4)));
typedef _Float16 f16x2 __attribute__((ext_vector_type(2)));
typedef __fp16   h16x2 __attribute__((ext_vector_type(2)));
typedef float    f32x4 __attribute__((ext_vector_type(4)));
typedef float    f32x16 __attribute__((ext_vector_type(16)));

__device__ __forceinline__ f16x2 pk_f16(float a, float b) {
  h16x2 r = __builtin_amdgcn_cvt_pkrtz(a, b);
  return __builtin_bit_cast(f16x2, r);
}

__device__ __forceinline__ void gld16(const void* g, void* l) {
  __builtin_amdgcn_global_load_lds(
      (const __attribute__((address_space(1))) void*)g,
      (__attribute__((address_space(3))) void*)l, 16, 0, 0);
}

__device__ __forceinline__ float fast_exp2(float x) {
#if __has_builtin(__builtin_amdgcn_exp2f)
  return __builtin_amdgcn_exp2f(x);
#else
  return exp2f(x);
#endif
}

__device__ __forceinline__ int swap23(int x) {   // swap bits 2 and 3 (involution)
  return (x & ~12) | ((x & 4) << 1) | ((x & 8) >> 1);
}

// load 8 f32, pack to f16x8 (RTZ — identical to the old cvt_all pass)
__device__ __forceinline__ f16x8 cvt8(const float* __restrict__ p) {
  float4 x0 = *(const float4*)p;
  float4 x1 = *(const float4*)(p + 4);
  f16x2 c0 = pk_f16(x0.x, x0.y), c1 = pk_f16(x0.z, x0.w);
  f16x2 c2 = pk_f16(x1.x, x1.y), c3 = pk_f16(x1.z, x1.w);
  f16x8 h;
  h[0] = c0[0]; h[1] = c0[1]; h[2] = c1[0]; h[3] = c1[1];
  h[4] = c2[0]; h[5] = c2[1]; h[6] = c3[0]; h[7] = c3[1];
  return h;
}

// ---------------- 128x128-tile GEMM: C = (A @ W^T + bias)*oscale ----------------
// grid (m-blocks, n-blocks[, z]) -- m fastest so id%8 = m%8 (XCD-local A reuse).
// A32/B32: operand is f32 in global; converted during staging (reg-staged).
// VT=false: operand-swapped MFMA -> C-reg spans N -> vectorized stores.
template <typename OUT_T, bool VT, bool A32, bool B32>
__device__ __forceinline__ void gemm_core(
    const void* __restrict__ Av, const void* __restrict__ Wv,
    const float* __restrict__ bias, OUT_T* __restrict__ out, float oscale)
{
  const int tid  = threadIdx.x;
  const int l    = tid & 63;
  const int wv   = tid >> 6;
  const int c    = l & 15, quad = l >> 4;
  const int m0   = blockIdx.x * 128, n0 = blockIdx.y * 128;
  const int wm   = wv & 1, wn = wv >> 1;
  __shared__ _Float16 sA[128 * 64];
  __shared__ _Float16 sB[128 * 64];

  const _Float16* gA16[4]; const float* gA32[4];
  const _Float16* gB16[4]; const float* gB32[4];
#pragma unroll
  for (int p = 0; p < 4; ++p) {
    int s = tid + p * 256, r = s >> 3, g = (s & 7) ^ (r & 7);
    if constexpr (A32) gA32[p] = (const float*)Av + (size_t)(m0 + r) * DM + g * 8;
    else               gA16[p] = (const _Float16*)Av + (size_t)(m0 + r) * DM + g * 8;
    if constexpr (B32) gB32[p] = (const float*)Wv + (size_t)(n0 + r) * DM + g * 8;
    else               gB16[p] = (const _Float16*)Wv + (size_t)(n0 + r) * DM + g * 8;
  }
  const int cx = c & 7;

  f32x4 acc[4][4] = {};
  for (int k0 = 0; k0 < DM; k0 += 64) {
    __syncthreads();
    // async side first (stays in flight while cvt side does VALU work)
    if constexpr (!A32) {
#pragma unroll
      for (int p = 0; p < 4; ++p) gld16(gA16[p] + k0, sA + (tid + p * 256) * 8);
    }
    if constexpr (!B32) {
#pragma unroll
      for (int p = 0; p < 4; ++p) gld16(gB16[p] + k0, sB + (tid + p * 256) * 8);
    }
    if constexpr (A32) {
      f16x8 st[4];
#pragma unroll
      for (int p = 0; p < 4; ++p) st[p] = cvt8(gA32[p] + k0);
#pragma unroll
      for (int p = 0; p < 4; ++p) *(f16x8*)(sA + (tid + p * 256) * 8) = st[p];
    }
    if constexpr (B32) {
      f16x8 st[4];
#pragma unroll
      for (int p = 0; p < 4; ++p) st[p] = cvt8(gB32[p] + k0);
#pragma unroll
      for (int p = 0; p < 4; ++p) *(f16x8*)(sB + (tid + p * 256) * 8) = st[p];
    }
    __syncthreads();
#pragma unroll
    for (int ks = 0; ks < 2; ++ks) {
      f16x8 af[4], bf[4];
#pragma unroll
      for (int i = 0; i < 4; ++i)
        af[i] = *(const f16x8*)&sA[(wm * 64 + i * 16 + c) * 64 + ((ks * 4 + quad) ^ cx) * 8];
#pragma unroll
      for (int j = 0; j < 4; ++j)
        bf[j] = *(const f16x8*)&sB[(wn * 64 + j * 16 + c) * 64 + ((ks * 4 + quad) ^ cx) * 8];
#pragma unroll
      for (int i = 0; i < 4; ++i)
#pragma unroll
        for (int j = 0; j < 4; ++j) {
          if constexpr (VT)
            acc[i][j] = __builtin_amdgcn_mfma_f32_16x16x32_f16(af[i], bf[j], acc[i][j], 0, 0, 0);
          else
            acc[j][i] = __builtin_amdgcn_mfma_f32_16x16x32_f16(bf[j], af[i], acc[j][i], 0, 0, 0);
        }
    }
  }
  if constexpr (VT) {
#pragma unroll
    for (int j = 0; j < 4; ++j) {
      int col = n0 + wn * 64 + j * 16 + c;
      float bb = bias[col];
      int hh = col >> 6, dd = col & 63;
#pragma unroll
      for (int i = 0; i < 4; ++i) {
        int row = m0 + wm * 64 + i * 16 + quad * 4;
        int bb2 = row >> 11, ss = row & (S_LEN - 1);
        _Float16* dst = (_Float16*)out + ((size_t)(bb2 * NH + hh) * DKH + dd) * S_LEN + ss;
        f16x4 v4;
#pragma unroll
        for (int r = 0; r < 4; ++r) v4[r] = (_Float16)((acc[i][j][r] + bb) * oscale);
        *(f16x4*)dst = v4;
      }
    }
  } else {
    // acc[j][i][r] = C[m = m0+wm*64+i*16+c][n = n0+wn*64+j*16+quad*4+r]
#pragma unroll
    for (int j = 0; j < 4; ++j) {
      const int nb = n0 + wn * 64 + j * 16 + quad * 4;
      const f32x4 bb = *(const f32x4*)(bias + nb);
#pragma unroll
      for (int i = 0; i < 4; ++i) {
        const int m = m0 + wm * 64 + i * 16 + c;
        if constexpr (__is_same(OUT_T, float)) {
          f32x4 v4;
#pragma unroll
          for (int r = 0; r < 4; ++r) v4[r] = (acc[j][i][r] + bb[r]) * oscale;
          *(f32x4*)((float*)out + (size_t)m * DM + nb) = v4;
        } else {
          f16x4 v4;
#pragma unroll
          for (int r = 0; r < 4; ++r) v4[r] = (_Float16)((acc[j][i][r] + bb[r]) * oscale);
          *(f16x4*)((_Float16*)out + (size_t)m * DM + nb) = v4;
        }
      }
    }
  }
}

#define SC_Q (0.125f * 1.44269504088896340736f)   // 1/sqrt(64) * log2(e)

__global__ __launch_bounds__(256) void proj3(
    const float* __restrict__ xq, const float* __restrict__ xk, const float* __restrict__ xv,
    const float* __restrict__ wqp, const float* __restrict__ wkp, const float* __restrict__ wvp,
    const float* __restrict__ bq, const float* __restrict__ bk, const float* __restrict__ bv,
    _Float16* __restrict__ Q, _Float16* __restrict__ K, _Float16* __restrict__ Vt)
{
  const int z = blockIdx.z;
  if (z == 2) {
    gemm_core<_Float16, true, true, true>(xv, wvp, bv, Vt, 1.0f);
  } else if (z == 0) {
    gemm_core<_Float16, false, true, true>(xq, wqp, bq, Q, SC_Q);
  } else {
    gemm_core<_Float16, false, true, true>(xk, wkp, bk, K, 1.0f);
  }
}

__global__ __launch_bounds__(256) void out_gemm(
    const _Float16* __restrict__ ctx, const float* __restrict__ wo,
    const float* __restrict__ bo, float* __restrict__ out)
{
  gemm_core<float, false, false, true>(ctx, wo, bo, out, 1.0f);
}

// ---------------- fused flash attention (32x32 MFMA, register-resident P) -----
// R13 structure (best: 49.9us, conflicts 2.1M): grid (B*H, S/128) = (32, 16),
// bh fastest -> one bh's q-blocks share an XCD (FETCH ~12.4 MB).
// 4 waves = (wq in 2) x (wk in 2); wave owns 64 q-rows x 32 keys/iter.
// Shared double-buffered K/V tiles, 1 barrier point per iter.
__global__ __launch_bounds__(256, 2) void attn(
    const _Float16* __restrict__ Q, const _Float16* __restrict__ K,
    const _Float16* __restrict__ Vt, _Float16* __restrict__ ctx)
{
  const int tid = threadIdx.x;
  const int l   = tid & 63, wv = tid >> 6;
  const int lo5 = l & 31, hf = l >> 5;
  const int wq  = wv >> 1, wk = wv & 1;
  const int bh  = blockIdx.x;          // XCD-local: id%8 == bh%8
  const int q0  = blockIdx.y * 128;
  const int b   = bh >> 4, hd = bh & 15;
  __shared__ _Float16 sK[2][64 * 64];   // [slot-row][d], swizzled 16B blocks, rows permuted by swap23
  __shared__ _Float16 sV[2][64 * 64];   // [d][key], swizzled 16B blocks, natural

  // persistent Q B-frags: qf[qb][kc] = Q[q = q0+wq*64+qb*32+lo5][d = 16*kc+8*hf ..+8]
  f16x8 qf0[4], qf1[4];
  {
    const _Float16* Qg0 = Q + ((size_t)(b * S_LEN + q0 + wq * 64 + lo5)) * DM + hd * DKH + 8 * hf;
    const _Float16* Qg1 = Qg0 + (size_t)32 * DM;
#pragma unroll
    for (int kc = 0; kc < 4; ++kc) { qf0[kc] = *(const f16x8*)(Qg0 + 16 * kc);
                                     qf1[kc] = *(const f16x8*)(Qg1 + 16 * kc); }
  }

  f32x16 o0[2] = {}, o1[2] = {};
  float l0 = 0.f, l1 = 0.f;
  const f16x2 ones = {(_Float16)1.0f, (_Float16)1.0f};

  const _Float16* Kg0 = K + ((size_t)b * S_LEN) * DM + hd * DKH;
  const _Float16* Vg0 = Vt + ((size_t)bh * DKH) * S_LEN;

  // staging: 512 16B slots per tile per array; thread handles slots {tid, tid+256}.
  // slot s: LDS block s (linear); row r=s>>3; global block (s&7)^(r&7).
  // K global row = swap23(r) (row permutation); V rows are d (natural).
  const int sa = tid,       ra = sa >> 3, ba = (sa & 7) ^ (ra & 7);
  const int sb = tid + 256, rb = sb >> 3, bb = (sb & 7) ^ (rb & 7);
  const _Float16* gKa = Kg0 + (size_t)swap23(ra) * DM + ba * 8;
  const _Float16* gKb = Kg0 + (size_t)swap23(rb) * DM + bb * 8;
  const _Float16* gVa = Vg0 + (size_t)ra * S_LEN + ba * 8;
  const _Float16* gVb = Vg0 + (size_t)rb * S_LEN + bb * 8;
  const int rx = lo5 & 7;   // frag-read block xor (row & 7)

#define STAGE(t, bf) do {                                   \
    const size_t k0s = (size_t)(t) * 64;                    \
    gld16(gKa + k0s * DM, sK[bf] + sa * 8);                 \
    gld16(gKb + k0s * DM, sK[bf] + sb * 8);                 \
    gld16(gVa + k0s,      sV[bf] + sa * 8);                 \
    gld16(gVb + k0s,      sV[bf] + sb * 8);                 \
  } while (0)

  // prologue: tile 0 -> buf 0, drain, publish
  STAGE(0, 0);
  asm volatile("s_waitcnt vmcnt(0)" ::: "memory");
  __builtin_amdgcn_s_barrier();

  const int NT = S_LEN / 64;
  for (int kt = 0; kt < NT; ++kt) {
    const int cur = kt & 1;
    if (kt + 1 < NT) STAGE(kt + 1, cur ^ 1);

    const _Float16* sKc = sK[cur];
    const _Float16* sVc = sV[cur];

    // S^T for wk's 32-key block vs both q-blocks: one kf read feeds 2 mfma.
    f32x16 sA0 = {}, sA1 = {};
    __builtin_amdgcn_s_setprio(1);
#pragma unroll
    for (int kc = 0; kc < 4; ++kc) {
      f16x8 kf = *(const f16x8*)&sKc[(32 * wk + lo5) * 64 + ((2 * kc + hf) ^ rx) * 8];
      sA0 = __builtin_amdgcn_mfma_f32_32x32x16_f16(kf, qf0[kc], sA0, 0, 0, 0);
      sA1 = __builtin_amdgcn_mfma_f32_32x32x16_f16(kf, qf1[kc], sA1, 0, 0, 0);
    }
    __builtin_amdgcn_s_setprio(0);

    // P = 2^S, packed fp16 in C-reg order -> direct PV A-operand (swap23).
    f16x8 p0[2], p1[2];
#pragma unroll
    for (int half = 0; half < 2; ++half)
#pragma unroll
      for (int j2 = 0; j2 < 4; ++j2) {
        float a0 = fast_exp2(sA0[8 * half + 2 * j2]);
        float a1 = fast_exp2(sA0[8 * half + 2 * j2 + 1]);
        f16x2 pka = pk_f16(a0, a1);
        p0[half][2 * j2]     = pka[0];
        p0[half][2 * j2 + 1] = pka[1];
        l0 = __builtin_amdgcn_fdot2(__builtin_bit_cast(h16x2, pka),
                                    __builtin_bit_cast(h16x2, ones), l0, false);
        float b0 = fast_exp2(sA1[8 * half + 2 * j2]);
        float b1 = fast_exp2(sA1[8 * half + 2 * j2 + 1]);
        f16x2 pkb = pk_f16(b0, b1);
        p1[half][2 * j2]     = pkb[0];
        p1[half][2 * j2 + 1] = pkb[1];
        l1 = __builtin_amdgcn_fdot2(__builtin_bit_cast(h16x2, pkb),
                                    __builtin_bit_cast(h16x2, ones), l1, false);
      }

    // PV: one vf read feeds both q-blocks' O accumulators.
    __builtin_amdgcn_s_setprio(1);
#pragma unroll
    for (int db = 0; db < 2; ++db)
#pragma unroll
      for (int half = 0; half < 2; ++half) {
        const int kc2 = 2 * wk + half;
        f16x8 vf = *(const f16x8*)&sVc[(32 * db + lo5) * 64 + ((2 * kc2 + hf) ^ rx) * 8];
        o0[db] = __builtin_amdgcn_mfma_f32_32x32x16_f16(p0[half], vf, o0[db], 0, 0, 0);
        o1[db] = __builtin_amdgcn_mfma_f32_32x32x16_f16(p1[half], vf, o1[db], 0, 0, 0);
      }
    __builtin_amdgcn_s_setprio(0);

    if (kt + 1 < NT) {
      asm volatile("s_waitcnt vmcnt(0)" ::: "memory");
      __builtin_amdgcn_s_barrier();
    }
  }
#undef STAGE

  __syncthreads();   // compute done; LDS buffers dead -> merge scratch

  // per-wave row sums (partial over wk's 32 keys), combined across halves
  l0 += __shfl_xor(l0, 32);
  l1 += __shfl_xor(l1, 32);
  float* lbuf = (float*)&sV[0][0];     // [wq][qb][wk][32] = 256 floats (in sV, kept)
  float* obuf = (float*)&sK[0][0];     // 16 KB f32 scratch per db pass (all of sK)
  if (hf == 0) {
    lbuf[((wq * 2 + 0) * 2 + wk) * 32 + lo5] = l0;
    lbuf[((wq * 2 + 1) * 2 + wk) * 32 + lo5] = l1;
  }
  __syncthreads();

  // inverse row sums (both q-blocks), valid for all waves
  float inv0[16], inv1[16];
#pragma unroll
  for (int r = 0; r < 16; ++r) {
    int qq = 8 * (r >> 2) + 4 * hf + (r & 3);
    inv0[r] = 1.0f / (lbuf[((wq * 2 + 0) * 2 + 0) * 32 + qq] +
                      lbuf[((wq * 2 + 0) * 2 + 1) * 32 + qq]);
    inv1[r] = 1.0f / (lbuf[((wq * 2 + 1) * 2 + 0) * 32 + qq] +
                      lbuf[((wq * 2 + 1) * 2 + 1) * 32 + qq]);
  }

  _Float16* Og = ctx + ((size_t)(b * S_LEN + q0 + wq * 64)) * DM + hd * DKH;
#pragma unroll
  for (int db = 0; db < 2; ++db) {
    // pass: wk==1 publishes its partial o[.][db]; wk==0 adds + stores
    if (wk == 1) {
#pragma unroll
      for (int r = 0; r < 16; ++r) {
        int qq = 8 * (r >> 2) + 4 * hf + (r & 3);
        obuf[((wq * 2 + 0) * 32 + qq) * 32 + lo5] = o0[db][r];
        obuf[((wq * 2 + 1) * 32 + qq) * 32 + lo5] = o1[db][r];
      }
    }
    __syncthreads();
    if (wk == 0) {
#pragma unroll
      for (int r = 0; r < 16; ++r) {
        int qq = 8 * (r >> 2) + 4 * hf + (r & 3);
        float v0 = o0[db][r] + obuf[((wq * 2 + 0) * 32 + qq) * 32 + lo5];
        float v1 = o1[db][r] + obuf[((wq * 2 + 1) * 32 + qq) * 32 + lo5];
        Og[(size_t)qq * DM + 32 * db + lo5]        = (_Float16)(v0 * inv0[r]);
        Og[(size_t)(32 + qq) * DM + 32 * db + lo5] = (_Float16)(v1 * inv1[r]);
      }
    }
    __syncthreads();   // obuf free for next db pass
  }
}

extern "C" void kernel_launch(void* const* d_in, const int* in_sizes, int n_in,
                              void* d_out, int out_size, void* d_ws, size_t ws_size,
                              hipStream_t stream)
{
  (void)in_sizes; (void)n_in; (void)out_size; (void)ws_size;
  const float* q  = (const float*)d_in[0];
  const float* k  = (const float*)d_in[1];
  const float* v  = (const float*)d_in[2];
  const float* wq = (const float*)d_in[3];
  const float* bq = (const float*)d_in[4];
  const float* wk = (const float*)d_in[5];
  const float* bk = (const float*)d_in[6];
  const float* wv = (const float*)d_in[7];
  const float* bv = (const float*)d_in[8];
  const float* wo = (const float*)d_in[9];
  const float* bo = (const float*)d_in[10];

  char* ws = (char*)d_ws;
  _Float16* CTX = (_Float16*)(ws);
  _Float16* Qp  = (_Float16*)(ws + (8u  << 20));
  _Float16* Kp  = (_Float16*)(ws + (16u << 20));
  _Float16* VT  = (_Float16*)(ws + (24u << 20));      // proj3 writes transposed V here
  float* out = (float*)d_out;

  proj3<<<dim3(32, 8, 3), 256, 0, stream>>>(q, k, v, wq, wk, wv, bq, bk, bv, Qp, Kp, VT);
  attn<<<dim3(32, 16), 256, 0, stream>>>(Qp, Kp, VT, CTX);
  out_gemm<<<dim3(32, 8), 256, 0, stream>>>(CTX, wo, bo, out);
}

// Round 7
// 222.944 us; speedup vs baseline: 1.0894x; 1.0894x over previous
//
#include <hip/hip_runtime.h>

// MHA: B=2, S=2048, D=1024, H=16, DK=64. All GEMMs are x @ W.T (+bias).
// R15: fix R14's proj3 collapse (88-95us, MfmaUtil 10%) -- the f32 reg-staging
//  was issued between the two barriers, exposing full load latency per K-step.
//  Now:
//  - cvt_w: tiny kernel converts the 4 weight mats f32->f16 (16MB, ~5us).
//  - proj3: A (activations) stays f32, reg-staged with T14 issue-early:
//    loads for tile k+1 issued AFTER the publish barrier -> in flight under
//    the whole MFMA phase; consumed by cvt at next loop top (implicit waitcnt).
//    B (weights f16) via global_load_lds into DOUBLE-BUFFERED sB, also issued
//    after the publish barrier -> zero exposed B latency. The per-iter
//    vmcnt(0) is free (cvt already drained older loads).
//  - shared hoisted to kernel scope: proj3 48KB (was 64KB via dual
//    instantiation), out_gemm 32KB.
//  - out_gemm: pure-f16 m97 path (ctx f16 + wo f16 from cvt_w).
//  - attn unchanged (49.9us local optimum; grid (bh, qblk) XCD-local).

#define S_LEN 2048
#define BATCH 2
#define DM    1024
#define NH    16
#define DKH   64
#define BS    (BATCH * S_LEN)   // 4096 rows

typedef _Float16 f16x8 __attribute__((ext_vector_type(8)));
typedef _Float16 f16x4 __attribute__((ext_vector_type(4)));
typedef _Float16 f16x2 __attribute__((ext_vector_type(2)));
typedef __fp16   h16x2 __attribute__((ext_vector_type(2)));
typedef float    f32x4 __attribute__((ext_vector_type(4)));
typedef float    f32x16 __attribute__((ext_vector_type(16)));

__device__ __forceinline__ f16x2 pk_f16(float a, float b) {
  h16x2 r = __builtin_amdgcn_cvt_pkrtz(a, b);
  return __builtin_bit_cast(f16x2, r);
}

__device__ __forceinline__ void gld16(const void* g, void* l) {
  __builtin_amdgcn_global_load_lds(
      (const __attribute__((address_space(1))) void*)g,
      (__attribute__((address_space(3))) void*)l, 16, 0, 0);
}

__device__ __forceinline__ float fast_exp2(float x) {
#if __has_builtin(__builtin_amdgcn_exp2f)
  return __builtin_amdgcn_exp2f(x);
#else
  return exp2f(x);
#endif
}

__device__ __forceinline__ int swap23(int x) {   // swap bits 2 and 3 (involution)
  return (x & ~12) | ((x & 4) << 1) | ((x & 8) >> 1);
}

// pack 8 f32 (two f32x4) -> f16x8, RTZ (bit-identical to the old cvt_all)
__device__ __forceinline__ f16x8 pack8(f32x4 a, f32x4 b) {
  f16x2 c0 = pk_f16(a[0], a[1]), c1 = pk_f16(a[2], a[3]);
  f16x2 c2 = pk_f16(b[0], b[1]), c3 = pk_f16(b[2], b[3]);
  f16x8 h;
  h[0] = c0[0]; h[1] = c0[1]; h[2] = c1[0]; h[3] = c1[1];
  h[4] = c2[0]; h[5] = c2[1]; h[6] = c3[0]; h[7] = c3[1];
  return h;
}

// ---------------- weight conversion f32 -> f16 (16 MB total) ----------------
__global__ __launch_bounds__(256) void cvt_w(
    const float* __restrict__ wq, const float* __restrict__ wk,
    const float* __restrict__ wv, const float* __restrict__ wo,
    _Float16* __restrict__ w16)
{
  const int y = blockIdx.y;
  const float* src = (y == 0) ? wq : (y == 1) ? wk : (y == 2) ? wv : wo;
  _Float16* dst = w16 + (size_t)y * (DM * DM);
  int i0 = (blockIdx.x * 256 + threadIdx.x) * 8;
  f32x4 a = *(const f32x4*)(src + i0);
  f32x4 b = *(const f32x4*)(src + i0 + 4);
  *(f16x8*)(dst + i0) = pack8(a, b);
}

// ---------------- GEMM core, A = f32 (reg-staged, T14), B = f16 (gld16 dbuf) --
// C = (A @ W^T + bias)*oscale.  grid (m, n[, z]) -> XCD-local A reuse.
// VT=false: operand-swapped MFMA -> C-reg spans N -> vectorized stores.
template <typename OUT_T, bool VT>
__device__ __forceinline__ void gemm_a32(
    const float* __restrict__ A, const _Float16* __restrict__ W,
    const float* __restrict__ bias, OUT_T* __restrict__ out, float oscale,
    _Float16* sA, _Float16* sB)   // sA: 128*64, sB: 2 x 128*64
{
  const int tid  = threadIdx.x;
  const int l    = tid & 63;
  const int wv   = tid >> 6;
  const int c    = l & 15, quad = l >> 4;
  const int m0   = blockIdx.x * 128, n0 = blockIdx.y * 128;
  const int wm   = wv & 1, wn = wv >> 1;

  const float* gA[4]; const _Float16* gB[4];
#pragma unroll
  for (int p = 0; p < 4; ++p) {
    int s = tid + p * 256, r = s >> 3, g = (s & 7) ^ (r & 7);
    gA[p] = A + (size_t)(m0 + r) * DM + g * 8;
    gB[p] = W + (size_t)(n0 + r) * DM + g * 8;
  }
  const int cx = c & 7;

  f32x4 pa[8];
#define LOADA(k0) do {                                        \
    _Pragma("unroll")                                         \
    for (int p = 0; p < 4; ++p) {                             \
      pa[2 * p]     = *(const f32x4*)(gA[p] + (k0));          \
      pa[2 * p + 1] = *(const f32x4*)(gA[p] + (k0) + 4);      \
    } } while (0)

  // prologue: A tile 0 -> regs; B tile 0 -> sB buf0 (async)
  LOADA(0);
#pragma unroll
  for (int p = 0; p < 4; ++p) gld16(gB[p], sB + (tid + p * 256) * 8);

  f32x4 acc[4][4] = {};
  for (int k0 = 0, kt = 0; k0 < DM; k0 += 64, ++kt) {
    _Float16* sBc = sB + (kt & 1) * (128 * 64);
    _Float16* sBn = sB + ((kt & 1) ^ 1) * (128 * 64);

    // consume A tile kt from regs (compiler waitcnt drains ALL older loads,
    // including the B gld16s for this tile -> the vmcnt(0) below is free)
    f16x8 stA[4];
#pragma unroll
    for (int p = 0; p < 4; ++p) stA[p] = pack8(pa[2 * p], pa[2 * p + 1]);

    __syncthreads();                     // all waves done reading sA/sBc of kt-1
#pragma unroll
    for (int p = 0; p < 4; ++p) *(f16x8*)(sA + (tid + p * 256) * 8) = stA[p];
    asm volatile("s_waitcnt vmcnt(0)" ::: "memory");   // B gld16s of tile kt
    __syncthreads();                     // publish sA + sBc (tile kt)

    // prefetch tile kt+1: in flight under the whole MFMA phase below
    if (k0 + 64 < DM) {
#pragma unroll
      for (int p = 0; p < 4; ++p) gld16(gB[p] + k0 + 64, sBn + (tid + p * 256) * 8);
      LOADA(k0 + 64);
    }

#pragma unroll
    for (int ks = 0; ks < 2; ++ks) {
      f16x8 af[4], bf[4];
#pragma unroll
      for (int i = 0; i < 4; ++i)
        af[i] = *(const f16x8*)&sA[(wm * 64 + i * 16 + c) * 64 + ((ks * 4 + quad) ^ cx) * 8];
#pragma unroll
      for (int j = 0; j < 4; ++j)
        bf[j] = *(const f16x8*)&sBc[(wn * 64 + j * 16 + c) * 64 + ((ks * 4 + quad) ^ cx) * 8];
#pragma unroll
      for (int i = 0; i < 4; ++i)
#pragma unroll
        for (int j = 0; j < 4; ++j) {
          if constexpr (VT)
            acc[i][j] = __builtin_amdgcn_mfma_f32_16x16x32_f16(af[i], bf[j], acc[i][j], 0, 0, 0);
          else
            acc[j][i] = __builtin_amdgcn_mfma_f32_16x16x32_f16(bf[j], af[i], acc[j][i], 0, 0, 0);
        }
    }
  }
#undef LOADA

  if constexpr (VT) {
#pragma unroll
    for (int j = 0; j < 4; ++j) {
      int col = n0 + wn * 64 + j * 16 + c;
      float bb = bias[col];
      int hh = col >> 6, dd = col & 63;
#pragma unroll
      for (int i = 0; i < 4; ++i) {
        int row = m0 + wm * 64 + i * 16 + quad * 4;
        int bb2 = row >> 11, ss = row & (S_LEN - 1);
        _Float16* dst = (_Float16*)out + ((size_t)(bb2 * NH + hh) * DKH + dd) * S_LEN + ss;
        f16x4 v4;
#pragma unroll
        for (int r = 0; r < 4; ++r) v4[r] = (_Float16)((acc[i][j][r] + bb) * oscale);
        *(f16x4*)dst = v4;
      }
    }
  } else {
    // acc[j][i][r] = C[m = m0+wm*64+i*16+c][n = n0+wn*64+j*16+quad*4+r]
#pragma unroll
    for (int j = 0; j < 4; ++j) {
      const int nb = n0 + wn * 64 + j * 16 + quad * 4;
      const f32x4 bb = *(const f32x4*)(bias + nb);
#pragma unroll
      for (int i = 0; i < 4; ++i) {
        const int m = m0 + wm * 64 + i * 16 + c;
        f16x4 v4;
#pragma unroll
        for (int r = 0; r < 4; ++r) v4[r] = (_Float16)((acc[j][i][r] + bb[r]) * oscale);
        *(f16x4*)((_Float16*)out + (size_t)m * DM + nb) = v4;
      }
    }
  }
}

// ---------------- GEMM core, both operands f16 (m97-style, single-buffered) --
template <typename OUT_T>
__device__ __forceinline__ void gemm_f16(
    const _Float16* __restrict__ A, const _Float16* __restrict__ W,
    const float* __restrict__ bias, OUT_T* __restrict__ out, float oscale,
    _Float16* sA, _Float16* sB)
{
  const int tid  = threadIdx.x;
  const int l    = tid & 63;
  const int wv   = tid >> 6;
  const int c    = l & 15, quad = l >> 4;
  const int m0   = blockIdx.x * 128, n0 = blockIdx.y * 128;
  const int wm   = wv & 1, wn = wv >> 1;

  const _Float16* gA[4]; const _Float16* gB[4];
#pragma unroll
  for (int p = 0; p < 4; ++p) {
    int s = tid + p * 256, r = s >> 3, g = (s & 7) ^ (r & 7);
    gA[p] = A + (size_t)(m0 + r) * DM + g * 8;
    gB[p] = W + (size_t)(n0 + r) * DM + g * 8;
  }
  const int cx = c & 7;

  f32x4 acc[4][4] = {};
  for (int k0 = 0; k0 < DM; k0 += 64) {
    __syncthreads();
#pragma unroll
    for (int p = 0; p < 4; ++p) {
      gld16(gA[p] + k0, sA + (tid + p * 256) * 8);
      gld16(gB[p] + k0, sB + (tid + p * 256) * 8);
    }
    asm volatile("s_waitcnt vmcnt(0)" ::: "memory");
    __syncthreads();
#pragma unroll
    for (int ks = 0; ks < 2; ++ks) {
      f16x8 af[4], bf[4];
#pragma unroll
      for (int i = 0; i < 4; ++i)
        af[i] = *(const f16x8*)&sA[(wm * 64 + i * 16 + c) * 64 + ((ks * 4 + quad) ^ cx) * 8];
#pragma unroll
      for (int j = 0; j < 4; ++j)
        bf[j] = *(const f16x8*)&sB[(wn * 64 + j * 16 + c) * 64 + ((ks * 4 + quad) ^ cx) * 8];
#pragma unroll
      for (int i = 0; i < 4; ++i)
#pragma unroll
        for (int j = 0; j < 4; ++j)
          acc[j][i] = __builtin_amdgcn_mfma_f32_16x16x32_f16(bf[j], af[i], acc[j][i], 0, 0, 0);
    }
  }
  // acc[j][i][r] = C[m][n0+wn*64+j*16+quad*4+r]
#pragma unroll
  for (int j = 0; j < 4; ++j) {
    const int nb = n0 + wn * 64 + j * 16 + quad * 4;
    const f32x4 bb = *(const f32x4*)(bias + nb);
#pragma unroll
    for (int i = 0; i < 4; ++i) {
      const int m = m0 + wm * 64 + i * 16 + c;
      if constexpr (__is_same(OUT_T, float)) {
        f32x4 v4;
#pragma unroll
        for (int r = 0; r < 4; ++r) v4[r] = (acc[j][i][r] + bb[r]) * oscale;
        *(f32x4*)((float*)out + (size_t)m * DM + nb) = v4;
      } else {
        f16x4 v4;
#pragma unroll
        for (int r = 0; r < 4; ++r) v4[r] = (_Float16)((acc[j][i][r] + bb[r]) * oscale);
        *(f16x4*)((_Float16*)out + (size_t)m * DM + nb) = v4;
      }
    }
  }
}

#define SC_Q (0.125f * 1.44269504088896340736f)   // 1/sqrt(64) * log2(e)

__global__ __launch_bounds__(256) void proj3(
    const float* __restrict__ xq, const float* __restrict__ xk, const float* __restrict__ xv,
    const _Float16* __restrict__ w16,
    const float* __restrict__ bq, const float* __restrict__ bk, const float* __restrict__ bv,
    _Float16* __restrict__ Q, _Float16* __restrict__ K, _Float16* __restrict__ Vt)
{
  __shared__ _Float16 smem[3 * 128 * 64];   // sA 16KB + sB dbuf 32KB = 48KB
  const int z = blockIdx.z;
  if (z == 2) {
    gemm_a32<_Float16, true>(xv, w16 + (size_t)2 * DM * DM, bv, Vt, 1.0f,
                             smem, smem + 128 * 64);
  } else if (z == 0) {
    gemm_a32<_Float16, false>(xq, w16, bq, Q, SC_Q, smem, smem + 128 * 64);
  } else {
    gemm_a32<_Float16, false>(xk, w16 + (size_t)DM * DM, bk, K, 1.0f,
                              smem, smem + 128 * 64);
  }
}

__global__ __launch_bounds__(256) void out_gemm(
    const _Float16* __restrict__ ctx, const _Float16* __restrict__ wo16,
    const float* __restrict__ bo, float* __restrict__ out)
{
  __shared__ _Float16 smem[2 * 128 * 64];   // 32KB
  gemm_f16<float>(ctx, wo16, bo, out, 1.0f, smem, smem + 128 * 64);
}

// ---------------- fused flash attention (32x32 MFMA, register-resident P) -----
// R13 structure (49.9us): grid (B*H, S/128) = (32, 16), bh fastest -> one bh's
// q-blocks share an XCD (FETCH ~12.4 MB). 4 waves = (wq in 2) x (wk in 2);
// wave owns 64 q-rows x 32 keys/iter. Shared dbuf K/V tiles, 1 barrier/iter.
__global__ __launch_bounds__(256, 2) void attn(
    const _Float16* __restrict__ Q, const _Float16* __restrict__ K,
    const _Float16* __restrict__ Vt, _Float16* __restrict__ ctx)
{
  const int tid = threadIdx.x;
  const int l   = tid & 63, wv = tid >> 6;
  const int lo5 = l & 31, hf = l >> 5;
  const int wq  = wv >> 1, wk = wv & 1;
  const int bh  = blockIdx.x;          // XCD-local: id%8 == bh%8
  const int q0  = blockIdx.y * 128;
  const int b   = bh >> 4, hd = bh & 15;
  __shared__ _Float16 sK[2][64 * 64];   // [slot-row][d], swizzled 16B blocks, rows permuted by swap23
  __shared__ _Float16 sV[2][64 * 64];   // [d][key], swizzled 16B blocks, natural

  // persistent Q B-frags: qf[qb][kc] = Q[q = q0+wq*64+qb*32+lo5][d = 16*kc+8*hf ..+8]
  f16x8 qf0[4], qf1[4];
  {
    const _Float16* Qg0 = Q + ((size_t)(b * S_LEN + q0 + wq * 64 + lo5)) * DM + hd * DKH + 8 * hf;
    const _Float16* Qg1 = Qg0 + (size_t)32 * DM;
#pragma unroll
    for (int kc = 0; kc < 4; ++kc) { qf0[kc] = *(const f16x8*)(Qg0 + 16 * kc);
                                     qf1[kc] = *(const f16x8*)(Qg1 + 16 * kc); }
  }

  f32x16 o0[2] = {}, o1[2] = {};
  float l0 = 0.f, l1 = 0.f;
  const f16x2 ones = {(_Float16)1.0f, (_Float16)1.0f};

  const _Float16* Kg0 = K + ((size_t)b * S_LEN) * DM + hd * DKH;
  const _Float16* Vg0 = Vt + ((size_t)bh * DKH) * S_LEN;

  const int sa = tid,       ra = sa >> 3, ba = (sa & 7) ^ (ra & 7);
  const int sb = tid + 256, rb = sb >> 3, bb = (sb & 7) ^ (rb & 7);
  const _Float16* gKa = Kg0 + (size_t)swap23(ra) * DM + ba * 8;
  const _Float16* gKb = Kg0 + (size_t)swap23(rb) * DM + bb * 8;
  const _Float16* gVa = Vg0 + (size_t)ra * S_LEN + ba * 8;
  const _Float16* gVb = Vg0 + (size_t)rb * S_LEN + bb * 8;
  const int rx = lo5 & 7;   // frag-read block xor (row & 7)

#define STAGE(t, bf) do {                                   \
    const size_t k0s = (size_t)(t) * 64;                    \
    gld16(gKa + k0s * DM, sK[bf] + sa * 8);                 \
    gld16(gKb + k0s * DM, sK[bf] + sb * 8);                 \
    gld16(gVa + k0s,      sV[bf] + sa * 8);                 \
    gld16(gVb + k0s,      sV[bf] + sb * 8);                 \
  } while (0)

  STAGE(0, 0);
  asm volatile("s_waitcnt vmcnt(0)" ::: "memory");
  __builtin_amdgcn_s_barrier();

  const int NT = S_LEN / 64;
  for (int kt = 0; kt < NT; ++kt) {
    const int cur = kt & 1;
    if (kt + 1 < NT) STAGE(kt + 1, cur ^ 1);

    const _Float16* sKc = sK[cur];
    const _Float16* sVc = sV[cur];

    f32x16 sA0 = {}, sA1 = {};
    __builtin_amdgcn_s_setprio(1);
#pragma unroll
    for (int kc = 0; kc < 4; ++kc) {
      f16x8 kf = *(const f16x8*)&sKc[(32 * wk + lo5) * 64 + ((2 * kc + hf) ^ rx) * 8];
      sA0 = __builtin_amdgcn_mfma_f32_32x32x16_f16(kf, qf0[kc], sA0, 0, 0, 0);
      sA1 = __builtin_amdgcn_mfma_f32_32x32x16_f16(kf, qf1[kc], sA1, 0, 0, 0);
    }
    __builtin_amdgcn_s_setprio(0);

    f16x8 p0[2], p1[2];
#pragma unroll
    for (int half = 0; half < 2; ++half)
#pragma unroll
      for (int j2 = 0; j2 < 4; ++j2) {
        float a0 = fast_exp2(sA0[8 * half + 2 * j2]);
        float a1 = fast_exp2(sA0[8 * half + 2 * j2 + 1]);
        f16x2 pka = pk_f16(a0, a1);
        p0[half][2 * j2]     = pka[0];
        p0[half][2 * j2 + 1] = pka[1];
        l0 = __builtin_amdgcn_fdot2(__builtin_bit_cast(h16x2, pka),
                                    __builtin_bit_cast(h16x2, ones), l0, false);
        float b0 = fast_exp2(sA1[8 * half + 2 * j2]);
        float b1 = fast_exp2(sA1[8 * half + 2 * j2 + 1]);
        f16x2 pkb = pk_f16(b0, b1);
        p1[half][2 * j2]     = pkb[0];
        p1[half][2 * j2 + 1] = pkb[1];
        l1 = __builtin_amdgcn_fdot2(__builtin_bit_cast(h16x2, pkb),
                                    __builtin_bit_cast(h16x2, ones), l1, false);
      }

    __builtin_amdgcn_s_setprio(1);
#pragma unroll
    for (int db = 0; db < 2; ++db)
#pragma unroll
      for (int half = 0; half < 2; ++half) {
        const int kc2 = 2 * wk + half;
        f16x8 vf = *(const f16x8*)&sVc[(32 * db + lo5) * 64 + ((2 * kc2 + hf) ^ rx) * 8];
        o0[db] = __builtin_amdgcn_mfma_f32_32x32x16_f16(p0[half], vf, o0[db], 0, 0, 0);
        o1[db] = __builtin_amdgcn_mfma_f32_32x32x16_f16(p1[half], vf, o1[db], 0, 0, 0);
      }
    __builtin_amdgcn_s_setprio(0);

    if (kt + 1 < NT) {
      asm volatile("s_waitcnt vmcnt(0)" ::: "memory");
      __builtin_amdgcn_s_barrier();
    }
  }
#undef STAGE

  __syncthreads();   // compute done; LDS buffers dead -> merge scratch

  l0 += __shfl_xor(l0, 32);
  l1 += __shfl_xor(l1, 32);
  float* lbuf = (float*)&sV[0][0];     // [wq][qb][wk][32] = 256 floats
  float* obuf = (float*)&sK[0][0];     // 16 KB f32 scratch per db pass
  if (hf == 0) {
    lbuf[((wq * 2 + 0) * 2 + wk) * 32 + lo5] = l0;
    lbuf[((wq * 2 + 1) * 2 + wk) * 32 + lo5] = l1;
  }
  __syncthreads();

  float inv0[16], inv1[16];
#pragma unroll
  for (int r = 0; r < 16; ++r) {
    int qq = 8 * (r >> 2) + 4 * hf + (r & 3);
    inv0[r] = 1.0f / (lbuf[((wq * 2 + 0) * 2 + 0) * 32 + qq] +
                      lbuf[((wq * 2 + 0) * 2 + 1) * 32 + qq]);
    inv1[r] = 1.0f / (lbuf[((wq * 2 + 1) * 2 + 0) * 32 + qq] +
                      lbuf[((wq * 2 + 1) * 2 + 1) * 32 + qq]);
  }

  _Float16* Og = ctx + ((size_t)(b * S_LEN + q0 + wq * 64)) * DM + hd * DKH;
#pragma unroll
  for (int db = 0; db < 2; ++db) {
    if (wk == 1) {
#pragma unroll
      for (int r = 0; r < 16; ++r) {
        int qq = 8 * (r >> 2) + 4 * hf + (r & 3);
        obuf[((wq * 2 + 0) * 32 + qq) * 32 + lo5] = o0[db][r];
        obuf[((wq * 2 + 1) * 32 + qq) * 32 + lo5] = o1[db][r];
      }
    }
    __syncthreads();
    if (wk == 0) {
#pragma unroll
      for (int r = 0; r < 16; ++r) {
        int qq = 8 * (r >> 2) + 4 * hf + (r & 3);
        float v0 = o0[db][r] + obuf[((wq * 2 + 0) * 32 + qq) * 32 + lo5];
        float v1 = o1[db][r] + obuf[((wq * 2 + 1) * 32 + qq) * 32 + lo5];
        Og[(size_t)qq * DM + 32 * db + lo5]        = (_Float16)(v0 * inv0[r]);
        Og[(size_t)(32 + qq) * DM + 32 * db + lo5] = (_Float16)(v1 * inv1[r]);
      }
    }
    __syncthreads();
  }
}

extern "C" void kernel_launch(void* const* d_in, const int* in_sizes, int n_in,
                              void* d_out, int out_size, void* d_ws, size_t ws_size,
                              hipStream_t stream)
{
  (void)in_sizes; (void)n_in; (void)out_size; (void)ws_size;
  const float* q  = (const float*)d_in[0];
  const float* k  = (const float*)d_in[1];
  const float* v  = (const float*)d_in[2];
  const float* wq = (const float*)d_in[3];
  const float* bq = (const float*)d_in[4];
  const float* wk = (const float*)d_in[5];
  const float* bk = (const float*)d_in[6];
  const float* wv = (const float*)d_in[7];
  const float* bv = (const float*)d_in[8];
  const float* wo = (const float*)d_in[9];
  const float* bo = (const float*)d_in[10];

  char* ws = (char*)d_ws;
  _Float16* CTX = (_Float16*)(ws);
  _Float16* Qp  = (_Float16*)(ws + (8u  << 20));
  _Float16* Kp  = (_Float16*)(ws + (16u << 20));
  _Float16* VT  = (_Float16*)(ws + (24u << 20));      // proj3 writes transposed V here
  _Float16* W16 = (_Float16*)(ws + (32u << 20));      // Wq,Wk,Wv,Wo (f16)
  float* out = (float*)d_out;

  cvt_w<<<dim3(512, 4), 256, 0, stream>>>(wq, wk, wv, wo, W16);
  proj3<<<dim3(32, 8, 3), 256, 0, stream>>>(q, k, v, W16, bq, bk, bv, Qp, Kp, VT);
  attn<<<dim3(32, 16), 256, 0, stream>>>(Qp, Kp, VT, CTX);
  out_gemm<<<dim3(32, 8), 256, 0, stream>>>(CTX, W16 + (size_t)3 * DM * DM, bo, out);
}